// Round 10
// baseline (120.818 us; speedup 1.0000x reference)
//
#include <hip/hip_runtime.h>
#include <cstdint>
#include <cstddef>

#define BB 8
#define CC 128
#define HH 96
#define WW 320
#define HW (HH*WW)        // 30720
#define NSEL 32
#define NSELH 16
#define K1CH 2            // chunks per plane in reduce
#define K4CH 8            // chunks per plane in K4

typedef float f32x4 __attribute__((ext_vector_type(4)));

__device__ __forceinline__ float sigmoidf_(float x) {
  return __builtin_amdgcn_rcpf(1.0f + __expf(-x));
}

// K1: read-ONLY per-(b,c,chunk) partial sums T, A, Q. No stores in the loop,
// nontemporal loads (skip L2 allocation of stream-once data), 5-deep ILP.
__global__ __launch_bounds__(256) void k_reduce(
    const float* __restrict__ x, double* __restrict__ partials) {
  int t = threadIdx.x;
  int chunk = blockIdx.x & (K1CH-1);
  int bc = blockIdx.x >> 1;
  const f32x4* __restrict__ xi = (const f32x4*)(x + (size_t)bc * HW);
  float tf = 0.0f, af = 0.0f, qf = 0.0f;
  // per chunk: 3840 float4 = 3 outer * 5 batch * 256 threads
  #pragma unroll 1
  for (int outer = 0; outer < 3; ++outer) {
    int base = chunk*3840 + outer*1280;
    f32x4 v[5];
    #pragma unroll
    for (int u = 0; u < 5; u++)
      v[u] = __builtin_nontemporal_load(&xi[base + u*256 + t]);
    __builtin_amdgcn_sched_barrier(0);   // keep the 5 loads batched
    #pragma unroll
    for (int u = 0; u < 5; u++) {
      int j = base + u*256 + t;
      int h = j / (WW/4);
      float d = 0.1f + (float)h * (0.9f/95.0f);
      float s0 = sigmoidf_(v[u].x), s1 = sigmoidf_(v[u].y);
      float s2 = sigmoidf_(v[u].z), s3 = sigmoidf_(v[u].w);
      float ts = (s0+s1)+(s2+s3);
      tf += ts;
      af += ts * d;
      qf += (s0*s0+s1*s1)+(s2*s2+s3*s3);
    }
  }
  __shared__ double sh[3][256];
  sh[0][t]=(double)tf; sh[1][t]=(double)af; sh[2][t]=(double)qf;
  __syncthreads();
  for (int ofs=128; ofs>0; ofs>>=1) {
    if (t < ofs) {
      sh[0][t]+=sh[0][t+ofs];
      sh[1][t]+=sh[1][t+ofs];
      sh[2][t]+=sh[2][t+ofs];
    }
    __syncthreads();
  }
  if (t==0) {
    int p = bc*K1CH + chunk;
    partials[p*3+0]=sh[0][0];
    partials[p*3+1]=sh[1][0];
    partials[p*3+2]=sh[2][0];
  }
}

// K2: fused select (block 0) + runs (blocks 1..20).
__global__ __launch_bounds__(128) void k_select_runs(
    const double* __restrict__ partials, const int* __restrict__ mask,
    int* __restrict__ idx, uint8_t* __restrict__ kk) {
  int t = threadIdx.x;
  if (blockIdx.x == 0) {
    int c = t;
    double T=0.0, A=0.0, Q=0.0;
    for (int b=0;b<BB;b++) {
      for (int ch=0; ch<K1CH; ch++) {
        int p = (b*CC + c)*K1CH + ch;
        T += partials[p*3+0];
        A += partials[p*3+1];
        Q += partials[p*3+2];
      }
    }
    double sn = sqrt(Q); if (sn < 1e-6) sn = 1e-6;
    double c1 = A / sn;
    double c2 = (T - A) / sn;
    __shared__ double s1[CC], s2[CC];
    s1[c]=c1; s2[c]=c2;
    __syncthreads();
    int r1=0, r2=0;
    for (int j=0;j<CC;j++) {
      r1 += (s1[j] > c1) || (s1[j]==c1 && j<c);
      r2 += (s2[j] > c2) || (s2[j]==c2 && j<c);
    }
    if (r1 < NSELH) idx[r1] = c;
    if (r2 < NSELH) idx[NSELH + r2] = c;
  } else {
    int colid = (blockIdx.x - 1)*128 + t;   // 20*128 = 2560 = BB*WW
    int b = colid / WW;
    int w = colid - b*WW;
    const int* __restrict__ mcol = mask + (size_t)b*HW + w;
    unsigned long long lo=0ull, hi=0ull;
    #pragma unroll
    for (int h=0; h<64; ++h) lo |= (unsigned long long)(mcol[h*WW]!=0) << h;
    #pragma unroll
    for (int h=64; h<95; ++h) hi |= (unsigned long long)(mcol[h*WW]!=0) << (h-64);
    uint8_t* __restrict__ kcol = kk + (size_t)b*HW + w;
    #pragma unroll
    for (int h=0; h<96; ++h) {
      unsigned long long s;
      if (h == 0)      s = lo;
      else if (h < 64) s = (lo >> h) | (hi << (64-h));
      else             s = hi >> (h-64);
      int run = __builtin_ctzll(~s | (1ull<<33));
      kcol[h*WW] = (uint8_t)(run > 32 ? 32 : run);
    }
  }
}

// K4: per-(b,selc,chunk) partial max |prop-sel|. Grid BB*NSEL*K4CH = 2048.
__global__ __launch_bounds__(256) void k_maxdiff(
    const float* __restrict__ x, const int* __restrict__ idx,
    const uint8_t* __restrict__ kk, float* __restrict__ pmax) {
  int chunk = blockIdx.x & (K4CH-1);
  int bc32 = blockIdx.x >> 3;       // b*32 + c
  int b = bc32 >> 5;
  int c = bc32 & 31;
  int ic = idx[c];
  const float* __restrict__ base = x + ((size_t)b*CC + ic)*HW;
  const uint8_t* __restrict__ kb = kk + (size_t)b*HW;
  float mx = 0.0f;
  int lo = chunk * (HW/4/K4CH), hiend = lo + (HW/4/K4CH);
  for (int j = lo + threadIdx.x; j < hiend; j += 256) {
    f32x4 sel = ((const f32x4*)base)[j];
    uchar4 kv  = ((const uchar4*)kb)[j];
    int h = j / (WW/4);
    int w4 = (j - h*(WW/4))*4;
    float p0 = base[(h+(int)kv.x)*WW + w4+0];
    float p1 = base[(h+(int)kv.y)*WW + w4+1];
    float p2 = base[(h+(int)kv.z)*WW + w4+2];
    float p3 = base[(h+(int)kv.w)*WW + w4+3];
    mx = fmaxf(mx, fmaxf(fmaxf(fabsf(p0-sel.x), fabsf(p1-sel.y)),
                         fmaxf(fabsf(p2-sel.z), fabsf(p3-sel.w))));
  }
  __shared__ float sh[256];
  sh[threadIdx.x]=mx; __syncthreads();
  for (int ofs=128; ofs>0; ofs>>=1) {
    if ((int)threadIdx.x<ofs) sh[threadIdx.x]=fmaxf(sh[threadIdx.x], sh[threadIdx.x+ofs]);
    __syncthreads();
  }
  if (threadIdx.x==0) pmax[blockIdx.x] = sh[0];
}

// K5: finalize mclip from chunk maxes, then
// w = max_c clip(|prop-sel|/mclip_c,0,1); refined = w*prop + (1-w)*sel.
// Runs after the bulk memcpy, overwriting the 32 selected planes.
__global__ __launch_bounds__(WW) void k_refine(
    const float* __restrict__ x, const int* __restrict__ idx,
    const uint8_t* __restrict__ kk, const float* __restrict__ pmax,
    float* __restrict__ out) {
  int bh = blockIdx.x;
  int b = bh / HH, h = bh - b*HH;
  int w = threadIdx.x;
  __shared__ int sidx[NSEL];
  __shared__ float smc[NSEL];
  if (threadIdx.x < NSEL) {
    int c = threadIdx.x;
    sidx[c] = idx[c];
    float m = 0.0f;
    #pragma unroll
    for (int ch=0; ch<K4CH; ch++) m = fmaxf(m, pmax[(b*NSEL + c)*K4CH + ch]);
    m *= 0.3f;
    if (m == 0.0f) m = 1.0f;
    smc[c] = m;
  }
  __syncthreads();
  int r = h + (int)kk[(size_t)bh*WW + w];
  float sel[NSEL], prop[NSEL];
  float wmax = 0.0f;
  #pragma unroll
  for (int c=0;c<NSEL;c++) {
    const float* __restrict__ base = x + ((size_t)b*CC + sidx[c])*HW;
    sel[c]  = base[h*WW + w];
    prop[c] = base[r*WW + w];
    float v = fabsf(prop[c]-sel[c]) / smc[c];
    wmax = fmaxf(wmax, fminf(v, 1.0f));
  }
  #pragma unroll
  for (int c=0;c<NSEL;c++) {
    float rf = wmax*prop[c] + (1.0f - wmax)*sel[c];
    out[((size_t)b*CC + sidx[c])*HW + h*WW + w] = rf;
  }
}

extern "C" void kernel_launch(void* const* d_in, const int* in_sizes, int n_in,
                              void* d_out, int out_size, void* d_ws, size_t ws_size,
                              hipStream_t stream) {
  const float* x   = (const float*)d_in[0];
  const int* mask  = (const int*)d_in[1];
  float* out       = (float*)d_out;

  char* ws = (char*)d_ws;
  double* partials = (double*)(ws);                       // 2048*3*8 = 49152 B
  int*    idx      = (int*)(ws + 49152);                  // 128 B
  float*  pmax     = (float*)(ws + 49152 + 128);          // 8192 B
  uint8_t* kk      = (uint8_t*)(ws + 49152 + 128 + 8192); // 245760 B

  k_reduce<<<BB*CC*K1CH, 256, 0, stream>>>(x, partials);
  // Bulk copy x -> out on the platform's optimized D2D path (graph memcpy
  // node / SDMA). Selected planes get overwritten by k_refine afterwards.
  hipMemcpyAsync(out, x, (size_t)BB*CC*HW*sizeof(float),
                 hipMemcpyDeviceToDevice, stream);
  k_select_runs<<<21, 128, 0, stream>>>(partials, mask, idx, kk);
  k_maxdiff<<<BB*NSEL*K4CH, 256, 0, stream>>>(x, idx, kk, pmax);
  k_refine<<<BB*HH, WW, 0, stream>>>(x, idx, kk, pmax, out);
}

// Round 11
// 95.602 us; speedup vs baseline: 1.2638x; 1.2638x over previous
//
#include <hip/hip_runtime.h>
#include <cstdint>
#include <cstddef>

#define BB 8
#define CC 128
#define HH 96
#define WW 320
#define HW (HH*WW)        // 30720
#define NSEL 32
#define NSELH 16
#define K1CH 2            // chunks per plane in K1
#define K4CH 8            // chunks per plane in K4

typedef float f32x4 __attribute__((ext_vector_type(4)));

__device__ __forceinline__ float sigmoidf_(float x) {
  return __builtin_amdgcn_rcpf(1.0f + __expf(-x));
}

// K1: fused copy x->out + per-(b,c,chunk) partial sums, with the READ done
// via global_load_lds (HBM/L3 -> LDS directly, bypassing the VGPR load-return
// path — the one mechanism untested across the six ~3.4 TB/s variants).
// Double-buffered 5-deep batches with counted vmcnt waits.
__global__ __launch_bounds__(256) void k_copy_reduce(
    const float* __restrict__ x, float* __restrict__ out,
    double* __restrict__ partials) {
  __shared__ float lbuf[2][5][4][256];   // 40 KB: [dbuf][u][wave][lane*4+e]
  int t = threadIdx.x;
  int wv = t >> 6;
  int lane = t & 63;
  int chunk = blockIdx.x & (K1CH-1);
  int bc = blockIdx.x >> 1;
  const float* __restrict__ xp = x + (size_t)bc * HW;
  f32x4* __restrict__ op = (f32x4*)(out + (size_t)bc * HW);
  float tf = 0.f, af = 0.f, qf = 0.f;

  // prologue: issue batch 0 (5 glds, 16 B/lane each)
  #pragma unroll
  for (int u = 0; u < 5; ++u) {
    const float* g = xp + (size_t)(chunk*3840 + u*256 + t) * 4;
    __builtin_amdgcn_global_load_lds(
        (const __attribute__((address_space(1))) void*)g,
        (__attribute__((address_space(3))) void*)&lbuf[0][u][wv][0], 16, 0, 0);
  }
  #pragma unroll 1
  for (int outer = 0; outer < 3; ++outer) {
    int buf = outer & 1;
    if (outer < 2) {
      #pragma unroll
      for (int u = 0; u < 5; ++u) {
        const float* g = xp + (size_t)(chunk*3840 + (outer+1)*1280 + u*256 + t) * 4;
        __builtin_amdgcn_global_load_lds(
            (const __attribute__((address_space(1))) void*)g,
            (__attribute__((address_space(3))) void*)&lbuf[buf^1][u][wv][0], 16, 0, 0);
      }
    }
    // counted waits: outstanding = {next batch} (+ previous stores at outer=1)
    if (outer == 0)      asm volatile("s_waitcnt vmcnt(5)" ::: "memory");
    else if (outer == 1) asm volatile("s_waitcnt vmcnt(10)" ::: "memory");
    else                 asm volatile("s_waitcnt vmcnt(5)" ::: "memory");
    __builtin_amdgcn_sched_barrier(0);   // rule 18: pin ops behind the waitcnt
    #pragma unroll
    for (int u = 0; u < 5; ++u) {
      f32x4 v = *(const f32x4*)&lbuf[buf][u][wv][lane*4];
      int j = chunk*3840 + outer*1280 + u*256 + t;
      op[j] = v;
      int h = j / 80;                     // WW/4 = 80
      float d = 0.1f + (float)h * (0.9f/95.0f);
      float s0 = sigmoidf_(v.x), s1 = sigmoidf_(v.y);
      float s2 = sigmoidf_(v.z), s3 = sigmoidf_(v.w);
      float ts = (s0+s1)+(s2+s3);
      tf += ts;
      af += ts * d;
      qf += (s0*s0+s1*s1)+(s2*s2+s3*s3);
    }
  }
  __syncthreads();                        // done with lbuf; reuse as scratch
  double* sh = (double*)&lbuf[0][0][0][0];  // 3*256 doubles = 6 KB
  sh[0*256+t]=(double)tf; sh[1*256+t]=(double)af; sh[2*256+t]=(double)qf;
  __syncthreads();
  for (int ofs=128; ofs>0; ofs>>=1) {
    if (t < ofs) {
      sh[0*256+t]+=sh[0*256+t+ofs];
      sh[1*256+t]+=sh[1*256+t+ofs];
      sh[2*256+t]+=sh[2*256+t+ofs];
    }
    __syncthreads();
  }
  if (t==0) {
    int p = bc*K1CH + chunk;
    partials[p*3+0]=sh[0];
    partials[p*3+1]=sh[256];
    partials[p*3+2]=sh[512];
  }
}

// K2: fused select (block 0) + runs (blocks 1..20).
__global__ __launch_bounds__(128) void k_select_runs(
    const double* __restrict__ partials, const int* __restrict__ mask,
    int* __restrict__ idx, uint8_t* __restrict__ kk) {
  int t = threadIdx.x;
  if (blockIdx.x == 0) {
    int c = t;
    double T=0.0, A=0.0, Q=0.0;
    for (int b=0;b<BB;b++) {
      for (int ch=0; ch<K1CH; ch++) {
        int p = (b*CC + c)*K1CH + ch;
        T += partials[p*3+0];
        A += partials[p*3+1];
        Q += partials[p*3+2];
      }
    }
    double sn = sqrt(Q); if (sn < 1e-6) sn = 1e-6;
    double c1 = A / sn;
    double c2 = (T - A) / sn;
    __shared__ double s1[CC], s2[CC];
    s1[c]=c1; s2[c]=c2;
    __syncthreads();
    int r1=0, r2=0;
    for (int j=0;j<CC;j++) {
      r1 += (s1[j] > c1) || (s1[j]==c1 && j<c);
      r2 += (s2[j] > c2) || (s2[j]==c2 && j<c);
    }
    if (r1 < NSELH) idx[r1] = c;
    if (r2 < NSELH) idx[NSELH + r2] = c;
  } else {
    int colid = (blockIdx.x - 1)*128 + t;   // 20*128 = 2560 = BB*WW
    int b = colid / WW;
    int w = colid - b*WW;
    const int* __restrict__ mcol = mask + (size_t)b*HW + w;
    unsigned long long lo=0ull, hi=0ull;
    #pragma unroll
    for (int h=0; h<64; ++h) lo |= (unsigned long long)(mcol[h*WW]!=0) << h;
    #pragma unroll
    for (int h=64; h<95; ++h) hi |= (unsigned long long)(mcol[h*WW]!=0) << (h-64);
    uint8_t* __restrict__ kcol = kk + (size_t)b*HW + w;
    #pragma unroll
    for (int h=0; h<96; ++h) {
      unsigned long long s;
      if (h == 0)      s = lo;
      else if (h < 64) s = (lo >> h) | (hi << (64-h));
      else             s = hi >> (h-64);
      int run = __builtin_ctzll(~s | (1ull<<33));
      kcol[h*WW] = (uint8_t)(run > 32 ? 32 : run);
    }
  }
}

// K4: per-(b,selc,chunk) partial max |prop-sel|. Grid BB*NSEL*K4CH = 2048.
__global__ __launch_bounds__(256) void k_maxdiff(
    const float* __restrict__ x, const int* __restrict__ idx,
    const uint8_t* __restrict__ kk, float* __restrict__ pmax) {
  int chunk = blockIdx.x & (K4CH-1);
  int bc32 = blockIdx.x >> 3;       // b*32 + c
  int b = bc32 >> 5;
  int c = bc32 & 31;
  int ic = idx[c];
  const float* __restrict__ base = x + ((size_t)b*CC + ic)*HW;
  const uint8_t* __restrict__ kb = kk + (size_t)b*HW;
  float mx = 0.0f;
  int lo = chunk * (HW/4/K4CH), hiend = lo + (HW/4/K4CH);
  for (int j = lo + threadIdx.x; j < hiend; j += 256) {
    f32x4 sel = ((const f32x4*)base)[j];
    uchar4 kv  = ((const uchar4*)kb)[j];
    int h = j / (WW/4);
    int w4 = (j - h*(WW/4))*4;
    float p0 = base[(h+(int)kv.x)*WW + w4+0];
    float p1 = base[(h+(int)kv.y)*WW + w4+1];
    float p2 = base[(h+(int)kv.z)*WW + w4+2];
    float p3 = base[(h+(int)kv.w)*WW + w4+3];
    mx = fmaxf(mx, fmaxf(fmaxf(fabsf(p0-sel.x), fabsf(p1-sel.y)),
                         fmaxf(fabsf(p2-sel.z), fabsf(p3-sel.w))));
  }
  __shared__ float sh[256];
  sh[threadIdx.x]=mx; __syncthreads();
  for (int ofs=128; ofs>0; ofs>>=1) {
    if ((int)threadIdx.x<ofs) sh[threadIdx.x]=fmaxf(sh[threadIdx.x], sh[threadIdx.x+ofs]);
    __syncthreads();
  }
  if (threadIdx.x==0) pmax[blockIdx.x] = sh[0];
}

// K5: finalize mclip from chunk maxes, then
// w = max_c clip(|prop-sel|/mclip_c,0,1); refined = w*prop + (1-w)*sel.
__global__ __launch_bounds__(WW) void k_refine(
    const float* __restrict__ x, const int* __restrict__ idx,
    const uint8_t* __restrict__ kk, const float* __restrict__ pmax,
    float* __restrict__ out) {
  int bh = blockIdx.x;
  int b = bh / HH, h = bh - b*HH;
  int w = threadIdx.x;
  __shared__ int sidx[NSEL];
  __shared__ float smc[NSEL];
  if (threadIdx.x < NSEL) {
    int c = threadIdx.x;
    sidx[c] = idx[c];
    float m = 0.0f;
    #pragma unroll
    for (int ch=0; ch<K4CH; ch++) m = fmaxf(m, pmax[(b*NSEL + c)*K4CH + ch]);
    m *= 0.3f;
    if (m == 0.0f) m = 1.0f;
    smc[c] = m;
  }
  __syncthreads();
  int r = h + (int)kk[(size_t)bh*WW + w];
  float sel[NSEL], prop[NSEL];
  float wmax = 0.0f;
  #pragma unroll
  for (int c=0;c<NSEL;c++) {
    const float* __restrict__ base = x + ((size_t)b*CC + sidx[c])*HW;
    sel[c]  = base[h*WW + w];
    prop[c] = base[r*WW + w];
    float v = fabsf(prop[c]-sel[c]) / smc[c];
    wmax = fmaxf(wmax, fminf(v, 1.0f));
  }
  #pragma unroll
  for (int c=0;c<NSEL;c++) {
    float rf = wmax*prop[c] + (1.0f - wmax)*sel[c];
    out[((size_t)b*CC + sidx[c])*HW + h*WW + w] = rf;
  }
}

extern "C" void kernel_launch(void* const* d_in, const int* in_sizes, int n_in,
                              void* d_out, int out_size, void* d_ws, size_t ws_size,
                              hipStream_t stream) {
  const float* x   = (const float*)d_in[0];
  const int* mask  = (const int*)d_in[1];
  float* out       = (float*)d_out;

  char* ws = (char*)d_ws;
  double* partials = (double*)(ws);                       // 2048*3*8 = 49152 B
  int*    idx      = (int*)(ws + 49152);                  // 128 B
  float*  pmax     = (float*)(ws + 49152 + 128);          // 8192 B
  uint8_t* kk      = (uint8_t*)(ws + 49152 + 128 + 8192); // 245760 B

  k_copy_reduce<<<BB*CC*K1CH, 256, 0, stream>>>(x, out, partials);
  k_select_runs<<<21, 128, 0, stream>>>(partials, mask, idx, kk);
  k_maxdiff<<<BB*NSEL*K4CH, 256, 0, stream>>>(x, idx, kk, pmax);
  k_refine<<<BB*HH, WW, 0, stream>>>(x, idx, kk, pmax, out);
}